// Round 5
// baseline (4574.540 us; speedup 1.0000x reference)
//
#include <hip/hip_runtime.h>

#define T_STEPS 256
#define BATCH   64
#define HID     1024
#define DIN     512
#define NCLS    1000
#define NBLK    128
#define HSZ     (BATCH * HID)

typedef __attribute__((ext_vector_type(8))) short  short8;  // 8 bf16
typedef __attribute__((ext_vector_type(4))) float  f32x4;   // MFMA C/D

__device__ __forceinline__ unsigned short rne_bf16(float f) {
    unsigned int u = __builtin_bit_cast(unsigned int, f);
    u += 0x7FFFu + ((u >> 16) & 1u);
    return (unsigned short)(u >> 16);
}
__device__ __forceinline__ float bf16_to_f(unsigned short h) {
    unsigned int u = ((unsigned int)h) << 16;
    return __builtin_bit_cast(float, u);
}

#define MFMA(a, b, c) __builtin_amdgcn_mfma_f32_16x16x32_bf16((a), (b), (c), 0, 0, 0)

// ---------------------------------------------------------------------------
// One launch per timestep; the KERNEL BOUNDARY is the sync (CP-sequenced,
// hardware flush/inv). Launch k (k = 0..T_STEPS):
//   blocks 0..63  (layer 1): H1[k] = relu(xproj[k] + Whh0·H1[k-1])
//   blocks 64..127(layer 2): H2[k-1] = relu(Wih1·H1[k-1] + Whh1·H2[k-2])
// Both halves consume ONLY launch k-1 outputs -> zero intra-kernel
// cross-block dependencies, no atomics, no device-scope ops, plain cached
// loads/stores throughout. Rationale: rounds 0/1/2/4 proved every in-kernel
// handoff protocol costs ~14-16 us/step regardless of structure; the kernel
// boundary is the one handoff mechanism not yet measured.
// Buffers: H1[t] in buf t&1; H2[t] in buf t&1 (2-deep each).
// Geometry per block: 32x32 output tile (ns = n-slice, mh = batch half),
// identical MFMA/reduce arithmetic to prior rounds (bit-identical results).
// ---------------------------------------------------------------------------
__global__ __launch_bounds__(512, 2)
void rnn_step(int k,
              const float* __restrict__ xproj,
              const unsigned short* __restrict__ whh0h, const unsigned short* __restrict__ whh0l,
              const unsigned short* __restrict__ wih1h, const unsigned short* __restrict__ wih1l,
              const unsigned short* __restrict__ whh1h, const unsigned short* __restrict__ whh1l,
              unsigned short* h1hi, unsigned short* h1lo,
              unsigned short* h2hi, unsigned short* h2lo,
              float* h2f) {
    __shared__ float red[8 * 1088];   // 34.8 KB, [wave][m:32][n:34]

    const int bid  = blockIdx.x;
    const int isL2 = bid >= 64;
    if (!isL2 && k >= T_STEPS) return;   // k = T_STEPS: layer-2 tail only
    if (isL2 && k == 0)        return;   // k = 0: layer-1 head only

    const int tid  = threadIdx.x;
    const int w    = tid >> 6;
    const int lane = tid & 63;
    const int l15  = lane & 15;
    const int kq   = (lane >> 4) * 8;
    const int rm   = tid >> 4;        // reduce row 0..31
    const int rn   = (tid * 2) & 31;  // reduce col pair

    const int rb = isL2 ? bid - 64 : bid;
    const int ns = rb >> 1;           // 0..31 n-slice
    const int mh = rb & 1;            // batch half
    const int nb = ns * 32;
    const int mb = mh * 32;

    if (!isL2) {
        // ---- layer 1: H1[k] from H1[k-1]; K = 1024, wave k-slice 128 ----
        const int kb = w * 128;
        short8 WH[2][4], WL[2][4];
#pragma unroll
        for (int c = 0; c < 4; ++c)
#pragma unroll
            for (int nt = 0; nt < 2; ++nt) {
                const size_t o = (size_t)(nb + nt * 16 + l15) * HID + kb + c * 32 + kq;
                WH[nt][c] = *(const short8*)(whh0h + o);
                WL[nt][c] = *(const short8*)(whh0l + o);
            }
        const float2 xi = *(const float2*)(xproj + (size_t)k * BATCH * HID +
                                           (size_t)(mb + rm) * HID + nb + rn);
        const unsigned short* hch = h1hi + (size_t)((k + 1) & 1) * HSZ;  // H1[k-1]
        const unsigned short* hcl = h1lo + (size_t)((k + 1) & 1) * HSZ;
        f32x4 acc[2][2] = {};
#pragma unroll
        for (int c = 0; c < 4; ++c) {
            short8 ah[2], al[2];
#pragma unroll
            for (int mt = 0; mt < 2; ++mt) {
                const size_t o = (size_t)(mb + mt * 16 + l15) * HID + kb + c * 32 + kq;
                ah[mt] = *(const short8*)(hch + o);
                al[mt] = *(const short8*)(hcl + o);
            }
#pragma unroll
            for (int mt = 0; mt < 2; ++mt)
#pragma unroll
                for (int nt = 0; nt < 2; ++nt) {
                    acc[mt][nt] = MFMA(ah[mt], WH[nt][c], acc[mt][nt]);
                    acc[mt][nt] = MFMA(al[mt], WH[nt][c], acc[mt][nt]);
                    acc[mt][nt] = MFMA(ah[mt], WL[nt][c], acc[mt][nt]);
                }
        }
#pragma unroll
        for (int mt = 0; mt < 2; ++mt)
#pragma unroll
            for (int nt = 0; nt < 2; ++nt)
#pragma unroll
                for (int i = 0; i < 4; ++i)
                    red[w * 1088 + (mt * 16 + (lane >> 4) * 4 + i) * 34 +
                        nt * 16 + l15] = acc[mt][nt][i];
        __syncthreads();
        {
            float s0 = xi.x, s1 = xi.y;
#pragma unroll
            for (int ww = 0; ww < 8; ++ww) {
                const float* rp = red + ww * 1088 + rm * 34 + rn;
                s0 += rp[0];
                s1 += rp[1];
            }
            const float v0 = fmaxf(s0, 0.f), v1 = fmaxf(s1, 0.f);
            const unsigned short h0 = rne_bf16(v0), h1 = rne_bf16(v1);
            const unsigned int hp = (unsigned int)h0 | ((unsigned int)h1 << 16);
            const unsigned int lp = (unsigned int)rne_bf16(v0 - bf16_to_f(h0)) |
                                    ((unsigned int)rne_bf16(v1 - bf16_to_f(h1)) << 16);
            const size_t o  = (size_t)(mb + rm) * HID + nb + rn;
            const size_t ob = (size_t)(k & 1) * HSZ;                     // H1[k]
            *(unsigned int*)(h1hi + ob + o) = hp;
            *(unsigned int*)(h1lo + ob + o) = lp;
        }
    } else {
        // ---- layer 2: H2[k-1] from H1[k-1], H2[k-2]; K = 2048 ----
        const unsigned short* ph = (w < 4) ? wih1h : whh1h;
        const unsigned short* pl = (w < 4) ? wih1l : whh1l;
        const int kb = (w & 3) * 256;
        short8 WH[2][8], WL[2][8];
#pragma unroll
        for (int c = 0; c < 8; ++c)
#pragma unroll
            for (int nt = 0; nt < 2; ++nt) {
                const size_t o = (size_t)(nb + nt * 16 + l15) * HID + kb + c * 32 + kq;
                WH[nt][c] = *(const short8*)(ph + o);
                WL[nt][c] = *(const short8*)(pl + o);
            }
        // A: waves 0-3 read H1[k-1] (buf (k-1)&1); waves 4-7 read H2[k-2] (buf k&1)
        const unsigned short* ash = (w < 4) ? h1hi + (size_t)((k + 1) & 1) * HSZ
                                            : h2hi + (size_t)(k & 1) * HSZ;
        const unsigned short* asl = (w < 4) ? h1lo + (size_t)((k + 1) & 1) * HSZ
                                            : h2lo + (size_t)(k & 1) * HSZ;
        f32x4 acc[2][2] = {};
#pragma unroll
        for (int c = 0; c < 8; ++c) {
            short8 ah[2], al[2];
#pragma unroll
            for (int mt = 0; mt < 2; ++mt) {
                const size_t o = (size_t)(mb + mt * 16 + l15) * HID + kb + c * 32 + kq;
                ah[mt] = *(const short8*)(ash + o);
                al[mt] = *(const short8*)(asl + o);
            }
#pragma unroll
            for (int mt = 0; mt < 2; ++mt)
#pragma unroll
                for (int nt = 0; nt < 2; ++nt) {
                    acc[mt][nt] = MFMA(ah[mt], WH[nt][c], acc[mt][nt]);
                    acc[mt][nt] = MFMA(al[mt], WH[nt][c], acc[mt][nt]);
                    acc[mt][nt] = MFMA(ah[mt], WL[nt][c], acc[mt][nt]);
                }
        }
#pragma unroll
        for (int mt = 0; mt < 2; ++mt)
#pragma unroll
            for (int nt = 0; nt < 2; ++nt)
#pragma unroll
                for (int i = 0; i < 4; ++i)
                    red[w * 1088 + (mt * 16 + (lane >> 4) * 4 + i) * 34 +
                        nt * 16 + l15] = acc[mt][nt][i];
        __syncthreads();
        {
            float s0 = 0.f, s1 = 0.f;
#pragma unroll
            for (int ww = 0; ww < 8; ++ww) {
                const float* rp = red + ww * 1088 + rm * 34 + rn;
                s0 += rp[0];
                s1 += rp[1];
            }
            const float v0 = fmaxf(s0, 0.f), v1 = fmaxf(s1, 0.f);
            const unsigned short h0 = rne_bf16(v0), h1 = rne_bf16(v1);
            const unsigned int hp = (unsigned int)h0 | ((unsigned int)h1 << 16);
            const unsigned int lp = (unsigned int)rne_bf16(v0 - bf16_to_f(h0)) |
                                    ((unsigned int)rne_bf16(v1 - bf16_to_f(h1)) << 16);
            const size_t o  = (size_t)(mb + rm) * HID + nb + rn;
            const size_t ob = (size_t)((k + 1) & 1) * HSZ;               // H2[k-1]
            *(unsigned int*)(h2hi + ob + o) = hp;
            *(unsigned int*)(h2lo + ob + o) = lp;
            if (k == T_STEPS) {   // H2[255] -> fp32 for fc
                float2 f2; f2.x = v0; f2.y = v1;
                *(float2*)(h2f + o) = f2;
            }
        }
    }
}

// ---------------------------------------------------------------------------
// Bulk x-projection: xproj[t][b][n] = sum_k x[b][t][k] * w_ih0[n][k],
// 3-pass Markidis with on-the-fly fp32->bf16 hi/lo split of x.
// grid (T, 4 n-quarters) x 512; wave w -> 32 cols, all 64 batch rows.
// ---------------------------------------------------------------------------
__global__ __launch_bounds__(512)
void xproj_gemm(const float* __restrict__ x,
                const unsigned short* __restrict__ wh,
                const unsigned short* __restrict__ wl,
                float* __restrict__ xproj) {
    const int t    = blockIdx.x;
    const int nq   = blockIdx.y;
    const int w    = threadIdx.x >> 6;
    const int lane = threadIdx.x & 63;
    const int l15  = lane & 15;
    const int kq   = (lane >> 4) * 8;
    const int n0   = nq * 256 + w * 32;

    f32x4 acc[4][2] = {};
    for (int c = 0; c < 16; ++c) {
        const int k = c * 32 + kq;
        short8 wfh[2], wfl[2];
#pragma unroll
        for (int nt = 0; nt < 2; ++nt) {
            const size_t o = (size_t)(n0 + nt * 16 + l15) * DIN + k;
            wfh[nt] = *(const short8*)(wh + o);
            wfl[nt] = *(const short8*)(wl + o);
        }
#pragma unroll
        for (int mt = 0; mt < 4; ++mt) {
            const float* xr = x + ((size_t)(mt * 16 + l15) * T_STEPS + t) * DIN + k;
            float4 a0 = *(const float4*)xr;
            float4 a1 = *(const float4*)(xr + 4);
            float f[8] = {a0.x, a0.y, a0.z, a0.w, a1.x, a1.y, a1.z, a1.w};
            short8 ah, al;
#pragma unroll
            for (int i = 0; i < 8; ++i) {
                unsigned short h = rne_bf16(f[i]);
                ah[i] = (short)h;
                al[i] = (short)rne_bf16(f[i] - bf16_to_f(h));
            }
#pragma unroll
            for (int nt = 0; nt < 2; ++nt) {
                acc[mt][nt] = MFMA(ah, wfh[nt], acc[mt][nt]);
                acc[mt][nt] = MFMA(al, wfh[nt], acc[mt][nt]);
                acc[mt][nt] = MFMA(ah, wfl[nt], acc[mt][nt]);
            }
        }
    }
    float* op = xproj + (size_t)t * BATCH * HID;
#pragma unroll
    for (int mt = 0; mt < 4; ++mt)
#pragma unroll
        for (int nt = 0; nt < 2; ++nt)
#pragma unroll
            for (int i = 0; i < 4; ++i) {
                const int m = mt * 16 + (lane >> 4) * 4 + i;
                const int n = n0 + nt * 16 + l15;
                op[(size_t)m * HID + n] = acc[mt][nt][i];
            }
}

__global__ void split_w(const float* __restrict__ src,
                        unsigned short* __restrict__ hi,
                        unsigned short* __restrict__ lo, int n) {
    int i = blockIdx.x * 256 + threadIdx.x;
    if (i < n) {
        float v = src[i];
        unsigned short h = rne_bf16(v);
        hi[i] = h;
        lo[i] = rne_bf16(v - bf16_to_f(h));
    }
}

__global__ void zero_kernel(int* __restrict__ p, int n) {
    int i = blockIdx.x * 256 + threadIdx.x;
    if (i < n) p[i] = 0;
}

__global__ void fc_kernel(const float* __restrict__ h2,
                          const float* __restrict__ w_fc,
                          float* __restrict__ out) {
    __shared__ float hs[HID];
    const int b = blockIdx.x;
    for (int i = threadIdx.x; i < HID; i += 256) hs[i] = h2[(size_t)b * HID + i];
    __syncthreads();
    const int c = blockIdx.y * 256 + threadIdx.x;
    if (c < NCLS) {
        const float* w = w_fc + (size_t)c * HID;
        float s = 0.f;
        for (int k = 0; k < HID; k += 4) {
            float4 wv = *(const float4*)(w + k);
            s += wv.x * hs[k] + wv.y * hs[k + 1] + wv.z * hs[k + 2] + wv.w * hs[k + 3];
        }
        out[(size_t)b * NCLS + c] = s;
    }
}

extern "C" void kernel_launch(void* const* d_in, const int* in_sizes, int n_in,
                              void* d_out, int out_size, void* d_ws, size_t ws_size,
                              hipStream_t stream) {
    const float* x     = (const float*)d_in[0];
    const float* w_ih0 = (const float*)d_in[1];
    const float* w_hh0 = (const float*)d_in[2];
    const float* w_ih1 = (const float*)d_in[3];
    const float* w_hh1 = (const float*)d_in[4];
    const float* w_fc  = (const float*)d_in[5];
    float* out = (float*)d_out;

    char* ws = (char*)d_ws;
    size_t off = 0;
    auto alloc = [&](size_t bytes) { char* p = ws + off; off += bytes; return p; };
    float*          xproj = (float*)alloc((size_t)T_STEPS * BATCH * HID * 4);  // 64 MB
    unsigned short* wih0h = (unsigned short*)alloc((size_t)DIN * HID * 2);
    unsigned short* wih0l = (unsigned short*)alloc((size_t)DIN * HID * 2);
    unsigned short* whh0h = (unsigned short*)alloc((size_t)HID * HID * 2);
    unsigned short* whh0l = (unsigned short*)alloc((size_t)HID * HID * 2);
    unsigned short* wih1h = (unsigned short*)alloc((size_t)HID * HID * 2);
    unsigned short* wih1l = (unsigned short*)alloc((size_t)HID * HID * 2);
    unsigned short* whh1h = (unsigned short*)alloc((size_t)HID * HID * 2);
    unsigned short* whh1l = (unsigned short*)alloc((size_t)HID * HID * 2);
    unsigned short* h1hi  = (unsigned short*)alloc(2 * HSZ * 2);  // 2-deep
    unsigned short* h1lo  = (unsigned short*)alloc(2 * HSZ * 2);
    unsigned short* h2hi  = (unsigned short*)alloc(2 * HSZ * 2);
    unsigned short* h2lo  = (unsigned short*)alloc(2 * HSZ * 2);
    float*          h2f   = (float*)alloc(HSZ * 4);

    // split weights to bf16 hi/lo
    split_w<<<(DIN * HID + 255) / 256, 256, 0, stream>>>(w_ih0, wih0h, wih0l, DIN * HID);
    split_w<<<(HID * HID + 255) / 256, 256, 0, stream>>>(w_hh0, whh0h, whh0l, HID * HID);
    split_w<<<(HID * HID + 255) / 256, 256, 0, stream>>>(w_ih1, wih1h, wih1l, HID * HID);
    split_w<<<(HID * HID + 255) / 256, 256, 0, stream>>>(w_hh1, whh1h, whh1l, HID * HID);

    // bulk x-projection (removes x from the recurrence critical path)
    xproj_gemm<<<dim3(T_STEPS, 4), 512, 0, stream>>>(x, wih0h, wih0l, xproj);

    // zero h states + h2f (contiguous tail region starting at h1hi)
    const int nzero = (4 * (2 * HSZ * 2) + HSZ * 4) / 4;
    zero_kernel<<<(nzero + 255) / 256, 256, 0, stream>>>((int*)h1hi, nzero);

    // one launch per timestep; kernel boundary = the recurrence sync
    for (int k = 0; k <= T_STEPS; ++k)
        rnn_step<<<NBLK, 512, 0, stream>>>(k, xproj,
                                           whh0h, whh0l,
                                           wih1h, wih1l, whh1h, whh1l,
                                           h1hi, h1lo, h2hi, h2lo, h2f);

    fc_kernel<<<dim3(64, 4), 256, 0, stream>>>(h2f, w_fc, out);
}

// Round 6
// 4359.302 us; speedup vs baseline: 1.0494x; 1.0494x over previous
//
#include <hip/hip_runtime.h>

#define T_STEPS 256
#define BATCH   64
#define HID     1024
#define DIN     512
#define NCLS    1000
#define NBLK    128
#define HSZ     (BATCH * HID)
#define POLL_MAX 10000L   // bounded: deadlock -> fast wrong answer, not a hang

typedef __attribute__((ext_vector_type(8))) short  short8;  // 8 bf16
typedef __attribute__((ext_vector_type(4))) float  f32x4;   // MFMA C/D
typedef unsigned long long u64;

__device__ __forceinline__ unsigned short rne_bf16(float f) {
    unsigned int u = __builtin_bit_cast(unsigned int, f);
    u += 0x7FFFu + ((u >> 16) & 1u);
    return (unsigned short)(u >> 16);
}
__device__ __forceinline__ float bf16_to_f(unsigned short h) {
    unsigned int u = ((unsigned int)h) << 16;
    return __builtin_bit_cast(float, u);
}

#define MFMA(a, b, c) __builtin_amdgcn_mfma_f32_16x16x32_bf16((a), (b), (c), 0, 0, 0)

// Device-coherent (agent-scope) state access (proven correct rounds 1-5).
__device__ __forceinline__ short8 ld_st8(const unsigned short* p) {
    u64 a = __hip_atomic_load((const u64*)p,       __ATOMIC_RELAXED, __HIP_MEMORY_SCOPE_AGENT);
    u64 b = __hip_atomic_load((const u64*)(p + 4), __ATOMIC_RELAXED, __HIP_MEMORY_SCOPE_AGENT);
    union { u64 q[2]; short8 v; } u;
    u.q[0] = a; u.q[1] = b;
    return u.v;
}
__device__ __forceinline__ void st_u32(unsigned short* p, unsigned int v) {
    __hip_atomic_store((unsigned int*)p, v, __ATOMIC_RELAXED, __HIP_MEMORY_SCOPE_AGENT);
}

// ---------------------------------------------------------------------------
// SINGLE-READER flag transport (the round-6 change).
// FLG[bid][64]: each block owns a private 256B row. Slots 0..31 = L1
// producer flags (by ns), slots 32..63 = L2 producer flags (by ns).
// Consumers poll ONLY their own row -> <=8 reader-waves per line, no IC
// queueing (rounds 0/2/4 had up to 1024 waves hammering 1-2 shared lines,
// ~1.1 req/cy -> saturated bank; that queueing was the 14-16 us/step).
// Producers fan out: wave 0's 64 lanes store the step number to the 64
// same-universe consumer rows (64 distinct lines, parallel, one-shot).
// Protocol semantics identical to round 4 (h1 4-deep, h2 2-deep):
//   L1 iter p:  gate L1f>=p (lanes<32), L2f>=p-3 (lanes>=32); publish p+1
//   L2 step p:  gate L1f>=p (lanes<32), L2f>=p-1 (lanes>=32); publish p
// ---------------------------------------------------------------------------
__device__ __forceinline__ void poll_row(const int* row, int ta, int tb, int lane) {
    const int t = (lane < 32) ? ta : tb;
    for (long it = 0; it < POLL_MAX; ++it) {
        int v = __hip_atomic_load(row + lane, __ATOMIC_RELAXED, __HIP_MEMORY_SCOPE_AGENT);
        if (__all(v >= t)) break;
        __builtin_amdgcn_s_sleep(1);
    }
    asm volatile("" ::: "memory");   // keep data loads below the poll
}

__global__ __launch_bounds__(512, 2)
void rnn_mfma(const float* __restrict__ xproj,
              const unsigned short* __restrict__ whh0h, const unsigned short* __restrict__ whh0l,
              const unsigned short* __restrict__ wih1h, const unsigned short* __restrict__ wih1l,
              const unsigned short* __restrict__ whh1h, const unsigned short* __restrict__ whh1l,
              unsigned short* h1hi, unsigned short* h1lo,
              unsigned short* h2hi, unsigned short* h2lo,
              float* h2f, int* flg) {
    __shared__ float red[8 * 1088];   // 34.8 KB, [wave][m:32][n:34]

    const int bid  = blockIdx.x;
    const int tid  = threadIdx.x;
    const int w    = tid >> 6;
    const int lane = tid & 63;
    const int l15  = lane & 15;
    const int kq   = (lane >> 4) * 8;
    const int rm   = tid >> 4;        // reduce row 0..31 (all 512 threads)
    const int rn   = (tid * 2) & 31;  // reduce col pair

    const int isL2 = bid >= 64;
    const int rb   = isL2 ? bid - 64 : bid;
    const int ns   = rb >> 1;         // 0..31 n-slice
    const int mh   = rb & 1;          // batch-half universe
    const int nb   = ns * 32;
    const int mb   = mh * 32;

    const int* myrow = flg + bid * 64;         // private poll row
    // fanout target for wave-0 lane i: consumer block (2*(i&31)+mh [+64])
    const int fan_c  = ((tid & 31) << 1) + mh + ((tid >= 32) ? 64 : 0);
    int* fan_ptr = flg + fan_c * 64 + (isL2 ? 32 + ns : ns);

    if (!isL2) {
        // ---------------- layer 1: K = 1024, wave k-slice 128 ----------------
        const int kb = w * 128;
        short8 WH[2][4], WL[2][4];
#pragma unroll
        for (int c = 0; c < 4; ++c)
#pragma unroll
            for (int nt = 0; nt < 2; ++nt) {
                const size_t o = (size_t)(nb + nt * 16 + l15) * HID + kb + c * 32 + kq;
                WH[nt][c] = *(const short8*)(whh0h + o);
                WL[nt][c] = *(const short8*)(whh0l + o);
            }
        for (int p = 0; p < T_STEPS; ++p) {
            // xproj prefetch (immutable, plain cacheable) BEFORE the poll
            const float2 xi = *(const float2*)(xproj + (size_t)p * BATCH * HID +
                                               (size_t)(mb + rm) * HID + nb + rn);
            poll_row(myrow, p, p - 3, lane);   // L1f>=p, L2f>=p-3
            const unsigned short* hch = h1hi + (size_t)(p & 3) * HSZ;
            const unsigned short* hcl = h1lo + (size_t)(p & 3) * HSZ;
            f32x4 acc[2][2] = {};
#pragma unroll
            for (int c = 0; c < 4; ++c) {
                short8 ah[2], al[2];
#pragma unroll
                for (int mt = 0; mt < 2; ++mt) {
                    const size_t o = (size_t)(mb + mt * 16 + l15) * HID + kb + c * 32 + kq;
                    ah[mt] = ld_st8(hch + o);
                    al[mt] = ld_st8(hcl + o);
                }
#pragma unroll
                for (int mt = 0; mt < 2; ++mt)
#pragma unroll
                    for (int nt = 0; nt < 2; ++nt) {
                        acc[mt][nt] = MFMA(ah[mt], WH[nt][c], acc[mt][nt]);
                        acc[mt][nt] = MFMA(al[mt], WH[nt][c], acc[mt][nt]);
                        acc[mt][nt] = MFMA(ah[mt], WL[nt][c], acc[mt][nt]);
                    }
            }
#pragma unroll
            for (int mt = 0; mt < 2; ++mt)
#pragma unroll
                for (int nt = 0; nt < 2; ++nt)
#pragma unroll
                    for (int i = 0; i < 4; ++i)
                        red[w * 1088 + (mt * 16 + (lane >> 4) * 4 + i) * 34 +
                            nt * 16 + l15] = acc[mt][nt][i];
            __syncthreads();
            {
                float s0 = xi.x, s1 = xi.y;
#pragma unroll
                for (int ww = 0; ww < 8; ++ww) {
                    const float* rp = red + ww * 1088 + rm * 34 + rn;
                    s0 += rp[0];
                    s1 += rp[1];
                }
                const float v0 = fmaxf(s0, 0.f), v1 = fmaxf(s1, 0.f);
                const unsigned short h0 = rne_bf16(v0), h1 = rne_bf16(v1);
                const unsigned int hp = (unsigned int)h0 | ((unsigned int)h1 << 16);
                const unsigned int lp = (unsigned int)rne_bf16(v0 - bf16_to_f(h0)) |
                                        ((unsigned int)rne_bf16(v1 - bf16_to_f(h1)) << 16);
                const size_t o  = (size_t)(mb + rm) * HID + nb + rn;
                const size_t ob = (size_t)((p + 1) & 3) * HSZ;
                st_u32(h1hi + ob + o, hp);
                st_u32(h1lo + ob + o, lp);
            }
            __syncthreads();   // vmcnt drain: data acked at IC before flags
            if (tid < 64)      // fanout publish: 64 lanes -> 64 consumer rows
                __hip_atomic_store(fan_ptr, p + 1, __ATOMIC_RELAXED,
                                   __HIP_MEMORY_SCOPE_AGENT);
        }
    } else {
        // ---------------- layer 2: K = 2048 (w<4: h1, w>=4: h2) ----------------
        const unsigned short* ph = (w < 4) ? wih1h : whh1h;
        const unsigned short* pl = (w < 4) ? wih1l : whh1l;
        const int kb = (w & 3) * 256;
        short8 WH[2][8], WL[2][8];
#pragma unroll
        for (int c = 0; c < 8; ++c)
#pragma unroll
            for (int nt = 0; nt < 2; ++nt) {
                const size_t o = (size_t)(nb + nt * 16 + l15) * HID + kb + c * 32 + kq;
                WH[nt][c] = *(const short8*)(ph + o);
                WL[nt][c] = *(const short8*)(pl + o);
            }
        for (int p = 1; p <= T_STEPS; ++p) {
            poll_row(myrow, p, p - 1, lane);   // L1f>=p, L2f>=p-1
            const unsigned short* ash = (w < 4) ? h1hi + (size_t)(p & 3) * HSZ
                                                : h2hi + (size_t)((p - 1) & 1) * HSZ;
            const unsigned short* asl = (w < 4) ? h1lo + (size_t)(p & 3) * HSZ
                                                : h2lo + (size_t)((p - 1) & 1) * HSZ;
            f32x4 acc[2][2] = {};
#pragma unroll
            for (int c = 0; c < 8; ++c) {
                short8 ah[2], al[2];
#pragma unroll
                for (int mt = 0; mt < 2; ++mt) {
                    const size_t o = (size_t)(mb + mt * 16 + l15) * HID + kb + c * 32 + kq;
                    ah[mt] = ld_st8(ash + o);
                    al[mt] = ld_st8(asl + o);
                }
#pragma unroll
                for (int mt = 0; mt < 2; ++mt)
#pragma unroll
                    for (int nt = 0; nt < 2; ++nt) {
                        acc[mt][nt] = MFMA(ah[mt], WH[nt][c], acc[mt][nt]);
                        acc[mt][nt] = MFMA(al[mt], WH[nt][c], acc[mt][nt]);
                        acc[mt][nt] = MFMA(ah[mt], WL[nt][c], acc[mt][nt]);
                    }
            }
#pragma unroll
            for (int mt = 0; mt < 2; ++mt)
#pragma unroll
                for (int nt = 0; nt < 2; ++nt)
#pragma unroll
                    for (int i = 0; i < 4; ++i)
                        red[w * 1088 + (mt * 16 + (lane >> 4) * 4 + i) * 34 +
                            nt * 16 + l15] = acc[mt][nt][i];
            __syncthreads();
            {
                float s0 = 0.f, s1 = 0.f;
#pragma unroll
                for (int ww = 0; ww < 8; ++ww) {
                    const float* rp = red + ww * 1088 + rm * 34 + rn;
                    s0 += rp[0];
                    s1 += rp[1];
                }
                const float v0 = fmaxf(s0, 0.f), v1 = fmaxf(s1, 0.f);
                const unsigned short h0 = rne_bf16(v0), h1 = rne_bf16(v1);
                const unsigned int hp = (unsigned int)h0 | ((unsigned int)h1 << 16);
                const unsigned int lp = (unsigned int)rne_bf16(v0 - bf16_to_f(h0)) |
                                        ((unsigned int)rne_bf16(v1 - bf16_to_f(h1)) << 16);
                const size_t o  = (size_t)(mb + rm) * HID + nb + rn;
                const size_t ob = (size_t)(p & 1) * HSZ;
                st_u32(h2hi + ob + o, hp);
                st_u32(h2lo + ob + o, lp);
                if (p == T_STEPS) {
                    float2 f2; f2.x = v0; f2.y = v1;
                    *(float2*)(h2f + o) = f2;
                }
            }
            __syncthreads();   // vmcnt drain before flags
            if (tid < 64)
                __hip_atomic_store(fan_ptr, p, __ATOMIC_RELAXED,
                                   __HIP_MEMORY_SCOPE_AGENT);
        }
    }
}

// ---------------------------------------------------------------------------
// Bulk x-projection: xproj[t][b][n] = sum_k x[b][t][k] * w_ih0[n][k],
// 3-pass Markidis with on-the-fly fp32->bf16 hi/lo split of x.
// ---------------------------------------------------------------------------
__global__ __launch_bounds__(512)
void xproj_gemm(const float* __restrict__ x,
                const unsigned short* __restrict__ wh,
                const unsigned short* __restrict__ wl,
                float* __restrict__ xproj) {
    const int t    = blockIdx.x;
    const int nq   = blockIdx.y;
    const int w    = threadIdx.x >> 6;
    const int lane = threadIdx.x & 63;
    const int l15  = lane & 15;
    const int kq   = (lane >> 4) * 8;
    const int n0   = nq * 256 + w * 32;

    f32x4 acc[4][2] = {};
    for (int c = 0; c < 16; ++c) {
        const int k = c * 32 + kq;
        short8 wfh[2], wfl[2];
#pragma unroll
        for (int nt = 0; nt < 2; ++nt) {
            const size_t o = (size_t)(n0 + nt * 16 + l15) * DIN + k;
            wfh[nt] = *(const short8*)(wh + o);
            wfl[nt] = *(const short8*)(wl + o);
        }
#pragma unroll
        for (int mt = 0; mt < 4; ++mt) {
            const float* xr = x + ((size_t)(mt * 16 + l15) * T_STEPS + t) * DIN + k;
            float4 a0 = *(const float4*)xr;
            float4 a1 = *(const float4*)(xr + 4);
            float f[8] = {a0.x, a0.y, a0.z, a0.w, a1.x, a1.y, a1.z, a1.w};
            short8 ah, al;
#pragma unroll
            for (int i = 0; i < 8; ++i) {
                unsigned short h = rne_bf16(f[i]);
                ah[i] = (short)h;
                al[i] = (short)rne_bf16(f[i] - bf16_to_f(h));
            }
#pragma unroll
            for (int nt = 0; nt < 2; ++nt) {
                acc[mt][nt] = MFMA(ah, wfh[nt], acc[mt][nt]);
                acc[mt][nt] = MFMA(al, wfh[nt], acc[mt][nt]);
                acc[mt][nt] = MFMA(ah, wfl[nt], acc[mt][nt]);
            }
        }
    }
    float* op = xproj + (size_t)t * BATCH * HID;
#pragma unroll
    for (int mt = 0; mt < 4; ++mt)
#pragma unroll
        for (int nt = 0; nt < 2; ++nt)
#pragma unroll
            for (int i = 0; i < 4; ++i) {
                const int m = mt * 16 + (lane >> 4) * 4 + i;
                const int n = n0 + nt * 16 + l15;
                op[(size_t)m * HID + n] = acc[mt][nt][i];
            }
}

__global__ void split_w(const float* __restrict__ src,
                        unsigned short* __restrict__ hi,
                        unsigned short* __restrict__ lo, int n) {
    int i = blockIdx.x * 256 + threadIdx.x;
    if (i < n) {
        float v = src[i];
        unsigned short h = rne_bf16(v);
        hi[i] = h;
        lo[i] = rne_bf16(v - bf16_to_f(h));
    }
}

__global__ void zero_kernel(int* __restrict__ p, int n) {
    int i = blockIdx.x * 256 + threadIdx.x;
    if (i < n) p[i] = 0;
}

__global__ void fc_kernel(const float* __restrict__ h2,
                          const float* __restrict__ w_fc,
                          float* __restrict__ out) {
    __shared__ float hs[HID];
    const int b = blockIdx.x;
    for (int i = threadIdx.x; i < HID; i += 256) hs[i] = h2[(size_t)b * HID + i];
    __syncthreads();
    const int c = blockIdx.y * 256 + threadIdx.x;
    if (c < NCLS) {
        const float* w = w_fc + (size_t)c * HID;
        float s = 0.f;
        for (int k = 0; k < HID; k += 4) {
            float4 wv = *(const float4*)(w + k);
            s += wv.x * hs[k] + wv.y * hs[k + 1] + wv.z * hs[k + 2] + wv.w * hs[k + 3];
        }
        out[(size_t)b * NCLS + c] = s;
    }
}

extern "C" void kernel_launch(void* const* d_in, const int* in_sizes, int n_in,
                              void* d_out, int out_size, void* d_ws, size_t ws_size,
                              hipStream_t stream) {
    const float* x     = (const float*)d_in[0];
    const float* w_ih0 = (const float*)d_in[1];
    const float* w_hh0 = (const float*)d_in[2];
    const float* w_ih1 = (const float*)d_in[3];
    const float* w_hh1 = (const float*)d_in[4];
    const float* w_fc  = (const float*)d_in[5];
    float* out = (float*)d_out;

    char* ws = (char*)d_ws;
    size_t off = 0;
    auto alloc = [&](size_t bytes) { char* p = ws + off; off += bytes; return p; };
    float*          xproj = (float*)alloc((size_t)T_STEPS * BATCH * HID * 4);  // 64 MB
    unsigned short* wih0h = (unsigned short*)alloc((size_t)DIN * HID * 2);
    unsigned short* wih0l = (unsigned short*)alloc((size_t)DIN * HID * 2);
    unsigned short* whh0h = (unsigned short*)alloc((size_t)HID * HID * 2);
    unsigned short* whh0l = (unsigned short*)alloc((size_t)HID * HID * 2);
    unsigned short* wih1h = (unsigned short*)alloc((size_t)HID * HID * 2);
    unsigned short* wih1l = (unsigned short*)alloc((size_t)HID * HID * 2);
    unsigned short* whh1h = (unsigned short*)alloc((size_t)HID * HID * 2);
    unsigned short* whh1l = (unsigned short*)alloc((size_t)HID * HID * 2);
    unsigned short* h1hi  = (unsigned short*)alloc(4 * HSZ * 2);  // 4-deep
    unsigned short* h1lo  = (unsigned short*)alloc(4 * HSZ * 2);
    unsigned short* h2hi  = (unsigned short*)alloc(2 * HSZ * 2);  // 2-deep
    unsigned short* h2lo  = (unsigned short*)alloc(2 * HSZ * 2);
    float*          h2f   = (float*)alloc(HSZ * 4);
    int*            flg   = (int*)alloc(32768);   // FLG[128][64] ints

    // split weights to bf16 hi/lo
    split_w<<<(DIN * HID + 255) / 256, 256, 0, stream>>>(w_ih0, wih0h, wih0l, DIN * HID);
    split_w<<<(HID * HID + 255) / 256, 256, 0, stream>>>(w_hh0, whh0h, whh0l, HID * HID);
    split_w<<<(HID * HID + 255) / 256, 256, 0, stream>>>(w_ih1, wih1h, wih1l, HID * HID);
    split_w<<<(HID * HID + 255) / 256, 256, 0, stream>>>(w_hh1, whh1h, whh1l, HID * HID);

    // bulk x-projection (removes x from the recurrence critical path)
    xproj_gemm<<<dim3(T_STEPS, 4), 512, 0, stream>>>(x, wih0h, wih0l, xproj);

    // zero h states + h2f + flags (contiguous tail region starting at h1hi)
    const int nzero = (4 * HSZ * 2 * 2 + 2 * HSZ * 2 * 2 + HSZ * 4 + 32768) / 4;
    zero_kernel<<<(nzero + 255) / 256, 256, 0, stream>>>((int*)h1hi, nzero);

    rnn_mfma<<<NBLK, 512, 0, stream>>>(xproj,
                                       whh0h, whh0l,
                                       wih1h, wih1l, whh1h, whh1l,
                                       h1hi, h1lo, h2hi, h2lo, h2f, flg);

    fc_kernel<<<dim3(64, 4), 256, 0, stream>>>(h2f, w_fc, out);
}

// Round 7
// 4320.111 us; speedup vs baseline: 1.0589x; 1.0091x over previous
//
#include <hip/hip_runtime.h>

#define T_STEPS 256
#define BATCH   64
#define HID     1024
#define DIN     512
#define NCLS    1000
#define NBLK    128
#define HSZ     (BATCH * HID)
#define POLL_MAX 10000L   // bounded: deadlock -> fast wrong answer, not a hang

typedef __attribute__((ext_vector_type(8))) short  short8;  // 8 bf16
typedef __attribute__((ext_vector_type(4))) float  f32x4;   // MFMA C/D

__device__ __forceinline__ unsigned short rne_bf16(float f) {
    unsigned int u = __builtin_bit_cast(unsigned int, f);
    u += 0x7FFFu + ((u >> 16) & 1u);
    return (unsigned short)(u >> 16);
}
__device__ __forceinline__ float bf16_to_f(unsigned short h) {
    unsigned int u = ((unsigned int)h) << 16;
    return __builtin_bit_cast(float, u);
}

#define MFMA(a, b, c) __builtin_amdgcn_mfma_f32_16x16x32_bf16((a), (b), (c), 0, 0, 0)

// Producer-side state stores stay agent-scope (write-through to IC) —
// proven correct R1-R6. CONSUMER loads are now PLAIN cached loads: the
// per-step acquire-agent fence (below) invalidates L1/L2 first, so they
// observe the IC-resident data, and the compiler pipelines them freely
// (R6's atomic loads were the suspected 12us serialization).
__device__ __forceinline__ void st_u32(unsigned short* p, unsigned int v) {
    __hip_atomic_store((unsigned int*)p, v, __ATOMIC_RELAXED, __HIP_MEMORY_SCOPE_AGENT);
}

// ---------------------------------------------------------------------------
// Single-reader flag transport (R6, kept verbatim). FLG[bid][64]: private
// 256B row per block; slots 0..31 = L1 producer flags, 32..63 = L2 flags.
// Protocol (h1 4-deep, h2 2-deep):
//   L1 iter p:  gate L1f>=p (lanes<32), L2f>=p-3 (lanes>=32); publish p+1
//   L2 step p:  gate L1f>=p (lanes<32), L2f>=p-1 (lanes>=32); publish p
// ---------------------------------------------------------------------------
__device__ __forceinline__ void poll_row(const int* row, int ta, int tb, int lane) {
    const int t = (lane < 32) ? ta : tb;
    for (long it = 0; it < POLL_MAX; ++it) {
        int v = __hip_atomic_load(row + lane, __ATOMIC_RELAXED, __HIP_MEMORY_SCOPE_AGENT);
        if (__all(v >= t)) break;
        __builtin_amdgcn_s_sleep(1);
    }
    // acquire-agent: s_waitcnt + buffer_inv (L1/L2 invalidate) so the PLAIN
    // state loads below observe the producers' IC-resident stores. Also a
    // compiler barrier: loads cannot hoist above the poll.
    __builtin_amdgcn_fence(__ATOMIC_ACQUIRE, "agent");
}

__global__ __launch_bounds__(512, 2)
void rnn_mfma(const float* __restrict__ xproj,
              const unsigned short* __restrict__ whh0h, const unsigned short* __restrict__ whh0l,
              const unsigned short* __restrict__ wih1h, const unsigned short* __restrict__ wih1l,
              const unsigned short* __restrict__ whh1h, const unsigned short* __restrict__ whh1l,
              unsigned short* h1hi, unsigned short* h1lo,
              unsigned short* h2hi, unsigned short* h2lo,
              float* h2f, int* flg) {
    __shared__ float red[8 * 1088];   // 34.8 KB, [wave][m:32][n:34]

    const int bid  = blockIdx.x;
    const int tid  = threadIdx.x;
    const int w    = tid >> 6;
    const int lane = tid & 63;
    const int l15  = lane & 15;
    const int kq   = (lane >> 4) * 8;
    const int rm   = tid >> 4;        // reduce row 0..31 (all 512 threads)
    const int rn   = (tid * 2) & 31;  // reduce col pair

    const int isL2 = bid >= 64;
    const int rb   = isL2 ? bid - 64 : bid;
    const int ns   = rb >> 1;         // 0..31 n-slice
    const int mh   = rb & 1;          // batch-half universe
    const int nb   = ns * 32;
    const int mb   = mh * 32;

    const int* myrow = flg + bid * 64;         // private poll row
    const int fan_c  = ((tid & 31) << 1) + mh + ((tid >= 32) ? 64 : 0);
    int* fan_ptr = flg + fan_c * 64 + (isL2 ? 32 + ns : ns);

    if (!isL2) {
        // ---------------- layer 1: K = 1024, wave k-slice 128 ----------------
        const int kb = w * 128;
        short8 WH[2][4], WL[2][4];
#pragma unroll
        for (int c = 0; c < 4; ++c)
#pragma unroll
            for (int nt = 0; nt < 2; ++nt) {
                const size_t o = (size_t)(nb + nt * 16 + l15) * HID + kb + c * 32 + kq;
                WH[nt][c] = *(const short8*)(whh0h + o);
                WL[nt][c] = *(const short8*)(whh0l + o);
            }
        for (int p = 0; p < T_STEPS; ++p) {
            // xproj prefetch (immutable, plain cacheable) BEFORE the poll
            const float2 xi = *(const float2*)(xproj + (size_t)p * BATCH * HID +
                                               (size_t)(mb + rm) * HID + nb + rn);
            poll_row(myrow, p, p - 3, lane);   // L1f>=p, L2f>=p-3 (+acquire)
            const unsigned short* hch = h1hi + (size_t)(p & 3) * HSZ;
            const unsigned short* hcl = h1lo + (size_t)(p & 3) * HSZ;
            f32x4 acc[2][2] = {};
#pragma unroll
            for (int c = 0; c < 4; ++c) {
                short8 ah[2], al[2];
#pragma unroll
                for (int mt = 0; mt < 2; ++mt) {
                    const size_t o = (size_t)(mb + mt * 16 + l15) * HID + kb + c * 32 + kq;
                    ah[mt] = *(const short8*)(hch + o);   // plain, pipelined
                    al[mt] = *(const short8*)(hcl + o);
                }
#pragma unroll
                for (int mt = 0; mt < 2; ++mt)
#pragma unroll
                    for (int nt = 0; nt < 2; ++nt) {
                        acc[mt][nt] = MFMA(ah[mt], WH[nt][c], acc[mt][nt]);
                        acc[mt][nt] = MFMA(al[mt], WH[nt][c], acc[mt][nt]);
                        acc[mt][nt] = MFMA(ah[mt], WL[nt][c], acc[mt][nt]);
                    }
            }
#pragma unroll
            for (int mt = 0; mt < 2; ++mt)
#pragma unroll
                for (int nt = 0; nt < 2; ++nt)
#pragma unroll
                    for (int i = 0; i < 4; ++i)
                        red[w * 1088 + (mt * 16 + (lane >> 4) * 4 + i) * 34 +
                            nt * 16 + l15] = acc[mt][nt][i];
            __syncthreads();
            {
                float s0 = xi.x, s1 = xi.y;
#pragma unroll
                for (int ww = 0; ww < 8; ++ww) {
                    const float* rp = red + ww * 1088 + rm * 34 + rn;
                    s0 += rp[0];
                    s1 += rp[1];
                }
                const float v0 = fmaxf(s0, 0.f), v1 = fmaxf(s1, 0.f);
                const unsigned short h0 = rne_bf16(v0), h1 = rne_bf16(v1);
                const unsigned int hp = (unsigned int)h0 | ((unsigned int)h1 << 16);
                const unsigned int lp = (unsigned int)rne_bf16(v0 - bf16_to_f(h0)) |
                                        ((unsigned int)rne_bf16(v1 - bf16_to_f(h1)) << 16);
                const size_t o  = (size_t)(mb + rm) * HID + nb + rn;
                const size_t ob = (size_t)((p + 1) & 3) * HSZ;
                st_u32(h1hi + ob + o, hp);
                st_u32(h1lo + ob + o, lp);
            }
            __syncthreads();   // vmcnt drain: data acked at IC before flags
            if (tid < 64)      // fanout publish: 64 lanes -> 64 consumer rows
                __hip_atomic_store(fan_ptr, p + 1, __ATOMIC_RELAXED,
                                   __HIP_MEMORY_SCOPE_AGENT);
        }
    } else {
        // ---------------- layer 2: K = 2048 (w<4: h1, w>=4: h2) ----------------
        const unsigned short* ph = (w < 4) ? wih1h : whh1h;
        const unsigned short* pl = (w < 4) ? wih1l : whh1l;
        const int kb = (w & 3) * 256;
        short8 WH[2][8], WL[2][8];
#pragma unroll
        for (int c = 0; c < 8; ++c)
#pragma unroll
            for (int nt = 0; nt < 2; ++nt) {
                const size_t o = (size_t)(nb + nt * 16 + l15) * HID + kb + c * 32 + kq;
                WH[nt][c] = *(const short8*)(ph + o);
                WL[nt][c] = *(const short8*)(pl + o);
            }
        for (int p = 1; p <= T_STEPS; ++p) {
            poll_row(myrow, p, p - 1, lane);   // L1f>=p, L2f>=p-1 (+acquire)
            const unsigned short* ash = (w < 4) ? h1hi + (size_t)(p & 3) * HSZ
                                                : h2hi + (size_t)((p - 1) & 1) * HSZ;
            const unsigned short* asl = (w < 4) ? h1lo + (size_t)(p & 3) * HSZ
                                                : h2lo + (size_t)((p - 1) & 1) * HSZ;
            f32x4 acc[2][2] = {};
#pragma unroll
            for (int c = 0; c < 8; ++c) {
                short8 ah[2], al[2];
#pragma unroll
                for (int mt = 0; mt < 2; ++mt) {
                    const size_t o = (size_t)(mb + mt * 16 + l15) * HID + kb + c * 32 + kq;
                    ah[mt] = *(const short8*)(ash + o);   // plain, pipelined
                    al[mt] = *(const short8*)(asl + o);
                }
#pragma unroll
                for (int mt = 0; mt < 2; ++mt)
#pragma unroll
                    for (int nt = 0; nt < 2; ++nt) {
                        acc[mt][nt] = MFMA(ah[mt], WH[nt][c], acc[mt][nt]);
                        acc[mt][nt] = MFMA(al[mt], WH[nt][c], acc[mt][nt]);
                        acc[mt][nt] = MFMA(ah[mt], WL[nt][c], acc[mt][nt]);
                    }
            }
#pragma unroll
            for (int mt = 0; mt < 2; ++mt)
#pragma unroll
                for (int nt = 0; nt < 2; ++nt)
#pragma unroll
                    for (int i = 0; i < 4; ++i)
                        red[w * 1088 + (mt * 16 + (lane >> 4) * 4 + i) * 34 +
                            nt * 16 + l15] = acc[mt][nt][i];
            __syncthreads();
            {
                float s0 = 0.f, s1 = 0.f;
#pragma unroll
                for (int ww = 0; ww < 8; ++ww) {
                    const float* rp = red + ww * 1088 + rm * 34 + rn;
                    s0 += rp[0];
                    s1 += rp[1];
                }
                const float v0 = fmaxf(s0, 0.f), v1 = fmaxf(s1, 0.f);
                const unsigned short h0 = rne_bf16(v0), h1 = rne_bf16(v1);
                const unsigned int hp = (unsigned int)h0 | ((unsigned int)h1 << 16);
                const unsigned int lp = (unsigned int)rne_bf16(v0 - bf16_to_f(h0)) |
                                        ((unsigned int)rne_bf16(v1 - bf16_to_f(h1)) << 16);
                const size_t o  = (size_t)(mb + rm) * HID + nb + rn;
                const size_t ob = (size_t)(p & 1) * HSZ;
                st_u32(h2hi + ob + o, hp);
                st_u32(h2lo + ob + o, lp);
                if (p == T_STEPS) {
                    float2 f2; f2.x = v0; f2.y = v1;
                    *(float2*)(h2f + o) = f2;
                }
            }
            __syncthreads();   // vmcnt drain before flags
            if (tid < 64)
                __hip_atomic_store(fan_ptr, p, __ATOMIC_RELAXED,
                                   __HIP_MEMORY_SCOPE_AGENT);
        }
    }
}

// ---------------------------------------------------------------------------
// Bulk x-projection: xproj[t][b][n] = sum_k x[b][t][k] * w_ih0[n][k],
// 3-pass Markidis with on-the-fly fp32->bf16 hi/lo split of x.
// ---------------------------------------------------------------------------
__global__ __launch_bounds__(512)
void xproj_gemm(const float* __restrict__ x,
                const unsigned short* __restrict__ wh,
                const unsigned short* __restrict__ wl,
                float* __restrict__ xproj) {
    const int t    = blockIdx.x;
    const int nq   = blockIdx.y;
    const int w    = threadIdx.x >> 6;
    const int lane = threadIdx.x & 63;
    const int l15  = lane & 15;
    const int kq   = (lane >> 4) * 8;
    const int n0   = nq * 256 + w * 32;

    f32x4 acc[4][2] = {};
    for (int c = 0; c < 16; ++c) {
        const int k = c * 32 + kq;
        short8 wfh[2], wfl[2];
#pragma unroll
        for (int nt = 0; nt < 2; ++nt) {
            const size_t o = (size_t)(n0 + nt * 16 + l15) * DIN + k;
            wfh[nt] = *(const short8*)(wh + o);
            wfl[nt] = *(const short8*)(wl + o);
        }
#pragma unroll
        for (int mt = 0; mt < 4; ++mt) {
            const float* xr = x + ((size_t)(mt * 16 + l15) * T_STEPS + t) * DIN + k;
            float4 a0 = *(const float4*)xr;
            float4 a1 = *(const float4*)(xr + 4);
            float f[8] = {a0.x, a0.y, a0.z, a0.w, a1.x, a1.y, a1.z, a1.w};
            short8 ah, al;
#pragma unroll
            for (int i = 0; i < 8; ++i) {
                unsigned short h = rne_bf16(f[i]);
                ah[i] = (short)h;
                al[i] = (short)rne_bf16(f[i] - bf16_to_f(h));
            }
#pragma unroll
            for (int nt = 0; nt < 2; ++nt) {
                acc[mt][nt] = MFMA(ah, wfh[nt], acc[mt][nt]);
                acc[mt][nt] = MFMA(al, wfh[nt], acc[mt][nt]);
                acc[mt][nt] = MFMA(ah, wfl[nt], acc[mt][nt]);
            }
        }
    }
    float* op = xproj + (size_t)t * BATCH * HID;
#pragma unroll
    for (int mt = 0; mt < 4; ++mt)
#pragma unroll
        for (int nt = 0; nt < 2; ++nt)
#pragma unroll
            for (int i = 0; i < 4; ++i) {
                const int m = mt * 16 + (lane >> 4) * 4 + i;
                const int n = n0 + nt * 16 + l15;
                op[(size_t)m * HID + n] = acc[mt][nt][i];
            }
}

__global__ void split_w(const float* __restrict__ src,
                        unsigned short* __restrict__ hi,
                        unsigned short* __restrict__ lo, int n) {
    int i = blockIdx.x * 256 + threadIdx.x;
    if (i < n) {
        float v = src[i];
        unsigned short h = rne_bf16(v);
        hi[i] = h;
        lo[i] = rne_bf16(v - bf16_to_f(h));
    }
}

__global__ void zero_kernel(int* __restrict__ p, int n) {
    int i = blockIdx.x * 256 + threadIdx.x;
    if (i < n) p[i] = 0;
}

__global__ void fc_kernel(const float* __restrict__ h2,
                          const float* __restrict__ w_fc,
                          float* __restrict__ out) {
    __shared__ float hs[HID];
    const int b = blockIdx.x;
    for (int i = threadIdx.x; i < HID; i += 256) hs[i] = h2[(size_t)b * HID + i];
    __syncthreads();
    const int c = blockIdx.y * 256 + threadIdx.x;
    if (c < NCLS) {
        const float* w = w_fc + (size_t)c * HID;
        float s = 0.f;
        for (int k = 0; k < HID; k += 4) {
            float4 wv = *(const float4*)(w + k);
            s += wv.x * hs[k] + wv.y * hs[k + 1] + wv.z * hs[k + 2] + wv.w * hs[k + 3];
        }
        out[(size_t)b * NCLS + c] = s;
    }
}

extern "C" void kernel_launch(void* const* d_in, const int* in_sizes, int n_in,
                              void* d_out, int out_size, void* d_ws, size_t ws_size,
                              hipStream_t stream) {
    const float* x     = (const float*)d_in[0];
    const float* w_ih0 = (const float*)d_in[1];
    const float* w_hh0 = (const float*)d_in[2];
    const float* w_ih1 = (const float*)d_in[3];
    const float* w_hh1 = (const float*)d_in[4];
    const float* w_fc  = (const float*)d_in[5];
    float* out = (float*)d_out;

    char* ws = (char*)d_ws;
    size_t off = 0;
    auto alloc = [&](size_t bytes) { char* p = ws + off; off += bytes; return p; };
    float*          xproj = (float*)alloc((size_t)T_STEPS * BATCH * HID * 4);  // 64 MB
    unsigned short* wih0h = (unsigned short*)alloc((size_t)DIN * HID * 2);
    unsigned short* wih0l = (unsigned short*)alloc((size_t)DIN * HID * 2);
    unsigned short* whh0h = (unsigned short*)alloc((size_t)HID * HID * 2);
    unsigned short* whh0l = (unsigned short*)alloc((size_t)HID * HID * 2);
    unsigned short* wih1h = (unsigned short*)alloc((size_t)HID * HID * 2);
    unsigned short* wih1l = (unsigned short*)alloc((size_t)HID * HID * 2);
    unsigned short* whh1h = (unsigned short*)alloc((size_t)HID * HID * 2);
    unsigned short* whh1l = (unsigned short*)alloc((size_t)HID * HID * 2);
    unsigned short* h1hi  = (unsigned short*)alloc(4 * HSZ * 2);  // 4-deep
    unsigned short* h1lo  = (unsigned short*)alloc(4 * HSZ * 2);
    unsigned short* h2hi  = (unsigned short*)alloc(2 * HSZ * 2);  // 2-deep
    unsigned short* h2lo  = (unsigned short*)alloc(2 * HSZ * 2);
    float*          h2f   = (float*)alloc(HSZ * 4);
    int*            flg   = (int*)alloc(32768);   // FLG[128][64] ints

    // split weights to bf16 hi/lo
    split_w<<<(DIN * HID + 255) / 256, 256, 0, stream>>>(w_ih0, wih0h, wih0l, DIN * HID);
    split_w<<<(HID * HID + 255) / 256, 256, 0, stream>>>(w_hh0, whh0h, whh0l, HID * HID);
    split_w<<<(HID * HID + 255) / 256, 256, 0, stream>>>(w_ih1, wih1h, wih1l, HID * HID);
    split_w<<<(HID * HID + 255) / 256, 256, 0, stream>>>(w_hh1, whh1h, whh1l, HID * HID);

    // bulk x-projection (removes x from the recurrence critical path)
    xproj_gemm<<<dim3(T_STEPS, 4), 512, 0, stream>>>(x, wih0h, wih0l, xproj);

    // zero h states + h2f + flags (contiguous tail region starting at h1hi)
    const int nzero = (4 * HSZ * 2 * 2 + 2 * HSZ * 2 * 2 + HSZ * 4 + 32768) / 4;
    zero_kernel<<<(nzero + 255) / 256, 256, 0, stream>>>((int*)h1hi, nzero);

    rnn_mfma<<<NBLK, 512, 0, stream>>>(xproj,
                                       whh0h, whh0l,
                                       wih1h, wih1l, whh1h, whh1l,
                                       h1hi, h1lo, h2hi, h2lo, h2f, flg);

    fc_kernel<<<dim3(64, 4), 256, 0, stream>>>(h2f, w_fc, out);
}